// Round 3
// baseline (244.048 us; speedup 1.0000x reference)
//
#include <hip/hip_runtime.h>
#include <hip/hip_bf16.h>

typedef __attribute__((ext_vector_type(8))) __bf16 bf16x8;
typedef __attribute__((ext_vector_type(4))) float f32x4;

#define N_SEQ   2048
#define N_BATCH 32
#define DIM_U   1024
#define DIM_A   512
#define NROWS   65536
#define MA_ELEMS ((size_t)NROWS * DIM_U) /* 67108864 */

__device__ __forceinline__ float tanh_fast(float x) {
    x = fminf(fmaxf(x, -15.f), 15.f);
    float e = __expf(2.f * x);
    return (e - 1.f) * __builtin_amdgcn_rcpf(e + 1.f);
}

// ---------------------------------------------------------------------------
// kernel 0: pack W (1024x512 f32) -> bf16 in GEMM B-stage order.
// 16B group F = (it*4 + ct)*1024 + s*128 + col  (it 0..15, ct 0..3, s 0..7,
// col 0..127); j 0..7: Wp[F*8+j] = W[(it*64 + (s>>2)*32 + (s&3)*8 + j)*512
//                                     + ct*128 + col]
__global__ void wpack_kernel(const float* __restrict__ W, __bf16* __restrict__ Wp) {
    int F = blockIdx.x * 256 + threadIdx.x;          // 0..65535
    int it  = F >> 12;
    int ct  = (F >> 10) & 3;
    int s   = (F >> 7) & 7;
    int col = F & 127;
    int k0  = it * 64 + (s >> 2) * 32 + (s & 3) * 8;
    int c   = ct * 128 + col;
    bf16x8 o;
#pragma unroll
    for (int j = 0; j < 8; ++j) o[j] = (__bf16)W[(k0 + j) * 512 + c];
    *reinterpret_cast<bf16x8*>(Wp + (size_t)F * 8) = o;
}

// ---------------------------------------------------------------------------
// kernel 1: partial scores. WG = 256 rows x 128 cols, K=1024, BK=64, 16 iters.
// 256 thr = 4 waves (2M x 2N); wave tile 128x64 = 8x4 16x16-frags, acc 128 VGPR.
// LDS 80KB: A dbuf 2x32KB (XOR-swizzled: addr = g*4096 + ((row^g)*16)),
// B 16KB single-buffered [slab s=kk*4+k16][col128][16B], restaged per iter via
// global_load_lds from pre-packed Wp. 2 blocks/CU anti-phase hides stage drain.
#define ABUF 32768
#define BBASE 65536

__global__ __launch_bounds__(256, 2) void score_gemm_kernel(
    const float* __restrict__ H, const __bf16* __restrict__ Wp,
    const float* __restrict__ Bb, const float* __restrict__ Uv,
    float* __restrict__ sp)
{
    __shared__ __align__(16) char lds[81920];
    const int tid  = threadIdx.x;
    const int lane = tid & 63;
    const int wid  = tid >> 6;     // 0..3
    const int c15  = lane & 15;
    const int hi   = lane >> 4;    // 0..3
    const int wr   = wid >> 1;     // M half
    const int wc   = wid & 1;      // N half

    // XCD-bijective swizzle (1024 % 8 == 0): the 4 ct-tiles of one mt land
    // adjacent on one XCD -> A-tile L2-hit for ct>0, Wp (1MB) L2-resident.
    const int bid = blockIdx.x;
    const int swz = (bid & 7) * 128 + (bid >> 3);
    const int mt = swz >> 2, ct = swz & 3;
    const long rowbase = (long)mt * 256;

    // --- A staging assignment: thread covers rows tr0 + i*32 (i=0..7), k-group tg
    const int tg  = tid & 7;            // g = k-group (8 bf16 = 16B)
    const int tr0 = tid >> 3;           // 0..31
    const float* aglob = H + (rowbase + tr0) * DIM_U + tg * 8;
    const int awoff = tg * 4096 + ((tr0 ^ tg) * 16);   // + buf*ABUF + i*512

    // --- B staging: 4 x global_load_lds(16B)/thread/iter
    const __bf16* wpl = Wp + ((size_t)ct * 1024 + wid * 64 + lane) * 8;

    // --- fragment read offsets (A swizzled; (r0+m*16)^g == (r0^g)+m*16)
    const int r0 = wr * 128 + c15;
    const int aoff0 = hi * 4096       + ((r0 ^ hi) * 16);        // kk=0: g=hi
    const int aoff1 = (4 + hi) * 4096 + ((r0 ^ (4 + hi)) * 16);  // kk=1: g=4+hi
    const int boff  = BBASE + hi * 2048 + (wc * 64 + c15) * 16;  // + kk*8192 + n*256

    f32x4 acc[8][4];
#pragma unroll
    for (int m = 0; m < 8; ++m)
#pragma unroll
        for (int n = 0; n < 4; ++n) acc[m][n] = f32x4{0.f, 0.f, 0.f, 0.f};

#define STAGE_B(it_) {                                                         \
        _Pragma("unroll")                                                      \
        for (int i_ = 0; i_ < 4; ++i_)                                         \
            __builtin_amdgcn_global_load_lds(                                  \
                (const __attribute__((address_space(1))) void*)(const void*)   \
                    (wpl + (size_t)(it_) * 32768 + i_ * 2048),                 \
                (__attribute__((address_space(3))) void*)(void*)               \
                    (lds + BBASE + i_ * 4096 + wid * 1024),                    \
                16, 0, 0); }

#define CVT_WRITE(i_, buf_) {                                                  \
        bf16x8 p = {(__bf16)LA[i_].x, (__bf16)LA[i_].y, (__bf16)LA[i_].z,      \
                    (__bf16)LA[i_].w, (__bf16)LB[i_].x, (__bf16)LB[i_].y,      \
                    (__bf16)LB[i_].z, (__bf16)LB[i_].w};                       \
        *reinterpret_cast<bf16x8*>(lds + (buf_) * ABUF + awoff + (i_) * 512) = p; }

    // ---- prologue: stage A(0) -> buf0, B(0)
    {
        f32x4 LA[8], LB[8];
#pragma unroll
        for (int i = 0; i < 8; ++i) {
            const float* p = aglob + i * (32 * DIM_U);
            LA[i] = *reinterpret_cast<const f32x4*>(p);
            LB[i] = *reinterpret_cast<const f32x4*>(p + 4);
        }
#pragma unroll
        for (int i = 0; i < 8; ++i) CVT_WRITE(i, 0);
        STAGE_B(0);
    }
    __syncthreads();

    for (int it = 0; it < 16; ++it) {
        const int cur = it & 1;
        const char* ab = lds + cur * ABUF;
        f32x4 LA[8], LB[8];
        // issue first half of next A-tile loads (hide under kk0 MFMA wall)
        if (it < 15) {
#pragma unroll
            for (int i = 0; i < 4; ++i) {
                const float* p = aglob + (it + 1) * 64 + i * (32 * DIM_U);
                LA[i] = *reinterpret_cast<const f32x4*>(p);
                LB[i] = *reinterpret_cast<const f32x4*>(p + 4);
            }
        }
        // ---- kk = 0
        {
            bf16x8 afr[8], bfr[4];
#pragma unroll
            for (int m = 0; m < 8; ++m)
                afr[m] = *reinterpret_cast<const bf16x8*>(ab + aoff0 + m * 256);
#pragma unroll
            for (int n = 0; n < 4; ++n)
                bfr[n] = *reinterpret_cast<const bf16x8*>(lds + boff + n * 256);
#pragma unroll
            for (int m = 0; m < 8; ++m)
#pragma unroll
                for (int n = 0; n < 4; ++n)
                    acc[m][n] = __builtin_amdgcn_mfma_f32_16x16x32_bf16(
                        afr[m], bfr[n], acc[m][n], 0, 0, 0);
        }
        // issue second half + retire first half into the idle A buffer
        if (it < 15) {
#pragma unroll
            for (int i = 4; i < 8; ++i) {
                const float* p = aglob + (it + 1) * 64 + i * (32 * DIM_U);
                LA[i] = *reinterpret_cast<const f32x4*>(p);
                LB[i] = *reinterpret_cast<const f32x4*>(p + 4);
            }
#pragma unroll
            for (int i = 0; i < 4; ++i) CVT_WRITE(i, cur ^ 1);
        }
        // ---- kk = 1
        {
            bf16x8 afr[8], bfr[4];
#pragma unroll
            for (int m = 0; m < 8; ++m)
                afr[m] = *reinterpret_cast<const bf16x8*>(ab + aoff1 + m * 256);
#pragma unroll
            for (int n = 0; n < 4; ++n)
                bfr[n] = *reinterpret_cast<const bf16x8*>(lds + boff + 8192 + n * 256);
#pragma unroll
            for (int m = 0; m < 8; ++m)
#pragma unroll
                for (int n = 0; n < 4; ++n)
                    acc[m][n] = __builtin_amdgcn_mfma_f32_16x16x32_bf16(
                        afr[m], bfr[n], acc[m][n], 0, 0, 0);
        }
        __syncthreads();               // all waves done reading B + A[cur^1] writes safe
        if (it < 15) {
            STAGE_B(it + 1);
#pragma unroll
            for (int i = 4; i < 8; ++i) CVT_WRITE(i, cur ^ 1);
        }
        __syncthreads();               // drains vmcnt/lgkmcnt (stage complete)
    }

    // ---- epilogue: tanh(acc + bias)*U, reduce over the WG's 128 cols
    float bias[4], uu[4];
#pragma unroll
    for (int n = 0; n < 4; ++n) {
        int col = ct * 128 + wc * 64 + n * 16 + c15;
        bias[n] = Bb[col];
        uu[n]   = Uv[col];
    }
    float* partial = reinterpret_cast<float*>(lds);  // [2 wc][256 rows] f32
#pragma unroll
    for (int m = 0; m < 8; ++m) {
        float pr[4];
#pragma unroll
        for (int r = 0; r < 4; ++r) pr[r] = 0.f;
#pragma unroll
        for (int n = 0; n < 4; ++n)
#pragma unroll
            for (int r = 0; r < 4; ++r)
                pr[r] += tanh_fast(acc[m][n][r] + bias[n]) * uu[n];
#pragma unroll
        for (int r = 0; r < 4; ++r) {
            float v = pr[r];
            v += __shfl_xor(v, 1); v += __shfl_xor(v, 2);
            v += __shfl_xor(v, 4); v += __shfl_xor(v, 8);
            if (c15 == 0)
                partial[wc * 256 + wr * 128 + m * 16 + hi * 4 + r] = v;
        }
    }
    __syncthreads();
    {
        float sc = partial[tid] + partial[256 + tid];
        sp[(size_t)ct * NROWS + rowbase + tid] = sc;
    }
}

// ---------------------------------------------------------------------------
// kernel 2: per-batch softmax over n=2048 (scores = sum of 4 N-partials)
__global__ void softmax_kernel(const float* __restrict__ sp, float* __restrict__ VU) {
    __shared__ float red[8];
    const int b = blockIdx.x, tid = threadIdx.x;
    const int lane = tid & 63, wid = tid >> 6;
    float v[8];
    float mx = -3.0e38f;
#pragma unroll
    for (int j = 0; j < 8; ++j) {
        int x = b * N_SEQ + tid + j * 256;
        v[j] = (sp[x] + sp[NROWS + x]) + (sp[2 * NROWS + x] + sp[3 * NROWS + x]);
        mx = fmaxf(mx, v[j]);
    }
#pragma unroll
    for (int off = 1; off < 64; off <<= 1) mx = fmaxf(mx, __shfl_xor(mx, off));
    if (lane == 0) red[wid] = mx;
    __syncthreads();
    mx = fmaxf(fmaxf(red[0], red[1]), fmaxf(red[2], red[3]));
    float e[8], sum = 0.f;
#pragma unroll
    for (int j = 0; j < 8; ++j) { e[j] = __expf(v[j] - mx); sum += e[j]; }
#pragma unroll
    for (int off = 1; off < 64; off <<= 1) sum += __shfl_xor(sum, off);
    if (lane == 0) red[4 + wid] = sum;
    __syncthreads();
    float total = (red[4] + red[5]) + (red[6] + red[7]);
    float rinv = 1.f / total;
#pragma unroll
    for (int j = 0; j < 8; ++j) VU[b * N_SEQ + tid + j * 256] = e[j] * rinv;
}

// ---------------------------------------------------------------------------
// kernel 3: Ma = H * VU (broadcast over u), float4 vectorized
__global__ void ma_kernel(const float* __restrict__ H, const float* __restrict__ VU,
                          float* __restrict__ Ma) {
    const int stride = gridDim.x * blockDim.x;
    const int n4 = (int)(MA_ELEMS / 4);
    for (int i4 = blockIdx.x * blockDim.x + threadIdx.x; i4 < n4; i4 += stride) {
        float sc = VU[i4 >> 8];                         // 256 float4 per row
        f32x4 h = reinterpret_cast<const f32x4*>(H)[i4];
        reinterpret_cast<f32x4*>(Ma)[i4] = h * sc;
    }
}

// ---------------------------------------------------------------------------
extern "C" void kernel_launch(void* const* d_in, const int* in_sizes, int n_in,
                              void* d_out, int out_size, void* d_ws, size_t ws_size,
                              hipStream_t stream) {
    const float* H  = (const float*)d_in[0];
    const float* W  = (const float*)d_in[1];
    const float* Bb = (const float*)d_in[2];
    const float* Uv = (const float*)d_in[3];

    float* out = (float*)d_out;
    float* Ma  = out;                          // 67108864 floats
    float* VU  = out + MA_ELEMS;               // 65536 floats
    // scratch inside the Ma region (ma_kernel overwrites it all at the end):
    float*  sp = out;                          // 4 x 65536 partial scores (1MB)
    __bf16* Wp = (__bf16*)(out + 4 * NROWS);   // 524288 bf16 (1MB)

    wpack_kernel<<<256, 256, 0, stream>>>(W, Wp);
    score_gemm_kernel<<<1024, 256, 0, stream>>>(H, Wp, Bb, Uv, sp);
    softmax_kernel<<<N_BATCH, 256, 0, stream>>>(sp, VU);
    ma_kernel<<<2048, 256, 0, stream>>>(H, VU, Ma);
}